// Round 1
// baseline (24.142 us; speedup 1.0000x reference)
//
#include <hip/hip_runtime.h>

// Problem geometry (f32):
//   x:   [8, 16, 3, 224, 224]
//   out: [8, 16, 224, 224, 3]  (permute 0,1,4,3,2)
// batch 0: y[0]=x[0]; y[t] = x[t] - 0.4*y[t-1] + 3   (elementwise c,h,w)
// batches 1..6: zeros
// batch 7: z[0]=0; z[t] = 3 - 0.4*z[t-1], broadcast over (w,h,c)

#define SP        150528    // 3*224*224 elements per (b,t) slice
#define BSTRIDE   2408448   // 16*SP elements per batch
#define TT        16
#define CH_STRIDE 50176     // 224*224

#define TILE_H 32
#define TILE_W 8
#define NWT    28           // 224/8
#define NTILES 196          // 7*28
#define LDW    9            // padded LDS row stride (floats)

#define FILL4   4214784     // 7 * 16*SP/4 float4s (batches 1..7)
#define BATCH4  602112      // 16*SP/4
#define TSLICE4 37632       // SP/4

__global__ __launch_bounds__(256) void temporal_fused(
    const float* __restrict__ x, float* __restrict__ out,
    int nblocks, int spread)
{
    const int tid = threadIdx.x;
    const int bid = blockIdx.x;

    __shared__ float lds[96 * LDW];   // 3*32 rows x 9 floats = 3456 B

    // ---------------- batch-0 recurrence + transpose tiles ----------------
    int tileid = ((bid % spread) == 0) ? (bid / spread) : -1;
    if (tileid >= NTILES) tileid = -1;

    if (tileid >= 0) {
        const int hb = tileid / NWT;
        const int wb = tileid - hb * NWT;
        const int h0 = hb * TILE_H;
        const int w0 = wb * TILE_W;

        // this thread owns one (h,w) point across c=0..2
        const int dw = tid & 7;        // w offset in tile
        const int hh = tid >> 3;       // h offset in tile (0..31)
        const int rbase = (h0 + hh) * 224 + w0 + dw;

        // t-invariant LDS write addresses
        const int wa0 = (0 * 32 + hh) * LDW + dw;
        const int wa1 = (1 * 32 + hh) * LDW + dw;
        const int wa2 = (2 * 32 + hh) * LDW + dw;

        // t-invariant reader mapping: j = tid + 256k over [0,768)
        int ra[3], oo[3];
        #pragma unroll
        for (int k = 0; k < 3; ++k) {
            int j  = tid + 256 * k;
            int ww = j / 96;
            int o  = j - ww * 96;       // = hh2*3 + c2
            int h2 = o / 3;
            int c2 = o - h2 * 3;
            ra[k] = (c2 * 32 + h2) * LDW + ww;   // LDS read addr
            oo[k] = ww * 672 + o;                // out offset within (t, tile)
        }
        const int ob0 = w0 * 672 + h0 * 3;

        // preload t=0
        float v0 = x[rbase];
        float v1 = x[rbase + CH_STRIDE];
        float v2 = x[rbase + 2 * CH_STRIDE];
        float y0 = 0.f, y1 = 0.f, y2 = 0.f;

        for (int t = 0; t < TT; ++t) {
            if (t == 0) { y0 = v0; y1 = v1; y2 = v2; }
            else {
                y0 = v0 - 0.4f * y0 + 3.0f;
                y1 = v1 - 0.4f * y1 + 3.0f;
                y2 = v2 - 0.4f * y2 + 3.0f;
            }
            // prefetch next t before barriers (hide HBM latency under stores)
            if (t + 1 < TT) {
                int rb = (t + 1) * SP + rbase;
                v0 = x[rb];
                v1 = x[rb + CH_STRIDE];
                v2 = x[rb + 2 * CH_STRIDE];
            }
            lds[wa0] = y0;
            lds[wa1] = y1;
            lds[wa2] = y2;
            __syncthreads();

            const int obase = t * SP + ob0;
            #pragma unroll
            for (int k = 0; k < 3; ++k)
                out[obase + oo[k]] = lds[ra[k]];
            __syncthreads();
        }
    }

    // ---------------- fill: batches 1..6 zeros, batch 7 broadcast z[t] ----
    float4* out4 = reinterpret_cast<float4*>(out + BSTRIDE); // batch-1 start
    const int gsz = nblocks * 256;
    for (int q = bid * 256 + tid; q < FILL4; q += gsz) {
        int bb = q / BATCH4;            // 0..6 -> batches 1..7
        float val = 0.0f;
        if (bb == 6) {                  // batch 7
            int r = q - bb * BATCH4;
            int t = r / TSLICE4;
            float z = 0.0f;
            for (int i = 0; i < t; ++i) z = 3.0f - 0.4f * z;
            val = z;
        }
        out4[q] = make_float4(val, val, val, val);
    }
}

extern "C" void kernel_launch(void* const* d_in, const int* in_sizes, int n_in,
                              void* d_out, int out_size, void* d_ws, size_t ws_size,
                              hipStream_t stream) {
    const float* x = (const float*)d_in[0];
    float* out = (float*)d_out;
    const int nblocks = 1960;   // 196 tiles spread every 10th block; ~7.7 blocks/CU
    const int spread = 10;
    temporal_fused<<<nblocks, 256, 0, stream>>>(x, out, nblocks, spread);
}